// Round 7
// baseline (627.245 us; speedup 1.0000x reference)
//
#include <hip/hip_runtime.h>
#include <hip/hip_bf16.h>

// Problem constants
#define B_TOTAL 131072

typedef short short8v __attribute__((ext_vector_type(8)));
typedef float f32x4 __attribute__((ext_vector_type(4)));

__device__ __forceinline__ unsigned short f2bf(float f) {   // RNE, prep only
  union { float f; unsigned u; } v; v.f = f;
  unsigned r = v.u + 0x7FFFu + ((v.u >> 16) & 1u);
  return (unsigned short)(r >> 16);
}

__device__ __forceinline__ unsigned short f2bf_hw(float f) { // hot path: HW cast
  __hip_bfloat16 h = __float2bfloat16(f);
  return *reinterpret_cast<unsigned short*>(&h);
}

__device__ __forceinline__ float bf2f(unsigned short u) {
  union { unsigned u; float f; } v; v.u = ((unsigned)u) << 16; return v.f;
}

__device__ __forceinline__ float frcp(float x) { return __builtin_amdgcn_rcpf(x); }

// XOR-swizzled ushort index within a [64][256] bf16 tile (16B-unit swizzle).
__device__ __forceinline__ int swz(int row, int col) {
  return row * 256 + (((col >> 3) ^ (row & 7)) << 3) + (col & 7);
}

// ws layout in bf16 elements
#define W_IN_OFF   0         // 256 x 32
#define W0A_OFF    8192      // 256 x 256
#define W1A_OFF    73728
#define W0B_OFF    139264
#define W1B_OFF    204800
#define WOUT_OFF   270336    // 768 x 256 (padded: row = dim*24 + j, j==23 zero)
#define WS_ELEMS   466944

__global__ void prep_weights(const float* __restrict__ w_in,
                             const float* __restrict__ w0a,
                             const float* __restrict__ w1a,
                             const float* __restrict__ w0b,
                             const float* __restrict__ w1b,
                             const float* __restrict__ w_out,
                             unsigned short* __restrict__ ws) {
  int idx = blockIdx.x * 256 + threadIdx.x;
  if (idx >= WS_ELEMS) return;
  float v;
  if (idx < W0A_OFF)       v = w_in[idx];
  else if (idx < W1A_OFF)  v = w0a[idx - W0A_OFF];
  else if (idx < W0B_OFF)  v = w1a[idx - W1A_OFF];
  else if (idx < W1B_OFF)  v = w0b[idx - W0B_OFF];
  else if (idx < WOUT_OFF) v = w1b[idx - W1B_OFF];
  else {
    int p = idx - WOUT_OFF;
    int row = p >> 8, k = p & 255;       // row < 768
    int dim = row / 24, j = row - dim * 24;
    v = (j < 23) ? w_out[(dim * 23 + j) * 256 + k] : 0.f;
  }
  ws[idx] = f2bf(v);
}

// 64 rows/WG, 4 waves. h fp32 in registers. ONE 32KB activation buffer
// (read-done barrier -> overwrite in place). Wave-private bf16 spline staging
// (2 dims/wave/chunk) -> no barriers in the whole output section.
// LDS 45KB -> 3 blocks/CU (12 waves/CU).
__global__ __launch_bounds__(256, 3)
void fused_main(const float* __restrict__ inp,
                const float* __restrict__ b_in,
                const float* __restrict__ b0a, const float* __restrict__ b1a,
                const float* __restrict__ b0b, const float* __restrict__ b1b,
                const float* __restrict__ b_out,
                const unsigned short* __restrict__ ws,
                float* __restrict__ outp) {
  __shared__ unsigned short Xs[64 * 256];      // 32768 B, swizzled
  __shared__ unsigned short Pstage[4 * 1536];  // 12288 B: per-wave [ds][row][24]
  __shared__ float Red[256];                   // 1024 B lad reduction

  const int tid  = threadIdx.x;
  const int lane = tid & 63;
  const int wave = tid >> 6;       // 0..3
  const int l15  = lane & 15;
  const int lhi  = lane >> 4;      // 0..3
  const int row0 = blockIdx.x * 64;

  const f32x4 zero4 = {0.f, 0.f, 0.f, 0.f};

  f32x4 hreg[4][4];   // fp32 h: row mi*16+lhi*4+r, col wave*64+ni*16+l15

  // ================= Layer in: h = ident @ w_in^T + b_in (K = 32) ===========
  {
#pragma unroll
    for (int mi = 0; mi < 4; mi++)
#pragma unroll
      for (int ni = 0; ni < 4; ni++) hreg[mi][ni] = zero4;

    short8v a[4];
#pragma unroll
    for (int mi = 0; mi < 4; mi++) {
      int rg = row0 + mi * 16 + l15;
      const float2* s2 = (const float2*)(inp + (long)rg * 64) + lhi * 8;
#pragma unroll
      for (int i = 0; i < 8; i++)
        a[mi][i] = (short)f2bf_hw(s2[i].y);   // odd cols = ident
    }
    short8v b[4];
#pragma unroll
    for (int ni = 0; ni < 4; ni++) {
      int col = wave * 64 + ni * 16 + l15;
      b[ni] = *(const short8v*)(ws + W_IN_OFF + col * 32 + lhi * 8);
    }
#pragma unroll
    for (int mi = 0; mi < 4; mi++)
#pragma unroll
      for (int ni = 0; ni < 4; ni++)
        hreg[mi][ni] = __builtin_amdgcn_mfma_f32_16x16x32_bf16(a[mi], b[ni], hreg[mi][ni], 0, 0, 0);

#pragma unroll
    for (int ni = 0; ni < 4; ni++) {
      int col = wave * 64 + ni * 16 + l15;
      float bias = b_in[col];
#pragma unroll
      for (int mi = 0; mi < 4; mi++)
#pragma unroll
        for (int r = 0; r < 4; r++) {
          hreg[mi][ni][r] += bias;
          int rl = mi * 16 + lhi * 4 + r;
          Xs[swz(rl, col)] = f2bf_hw(fmaxf(hreg[mi][ni][r], 0.f));
        }
    }
  }
  __syncthreads();

  // ================= 2 residual blocks (in-place X) =========================
#pragma unroll
  for (int blk = 0; blk < 2; ++blk) {
    const unsigned short* wAp = ws + (blk == 0 ? W0A_OFF : W0B_OFF);
    const unsigned short* wBp = ws + (blk == 0 ? W1A_OFF : W1B_OFF);
    const float* bAp = (blk == 0) ? b0a : b0b;
    const float* bBp = (blk == 0) ? b1a : b1b;

    // ---- step A: t = relu( X @ w0^T + b0 ); X <- t ----
    {
      f32x4 acc[4][4];
#pragma unroll
      for (int mi = 0; mi < 4; mi++)
#pragma unroll
        for (int ni = 0; ni < 4; ni++) acc[mi][ni] = zero4;

      for (int kk = 0; kk < 8; ++kk) {
        const int su = ((kk * 4 + lhi) ^ (l15 & 7)) << 3;
        short8v a[4], b[4];
#pragma unroll
        for (int mi = 0; mi < 4; mi++)
          a[mi] = *(const short8v*)&Xs[(mi * 16 + l15) * 256 + su];
#pragma unroll
        for (int ni = 0; ni < 4; ni++)
          b[ni] = *(const short8v*)(wAp + (wave * 64 + ni * 16 + l15) * 256 + kk * 32 + lhi * 8);
#pragma unroll
        for (int mi = 0; mi < 4; mi++)
#pragma unroll
          for (int ni = 0; ni < 4; ni++)
            acc[mi][ni] = __builtin_amdgcn_mfma_f32_16x16x32_bf16(a[mi], b[ni], acc[mi][ni], 0, 0, 0);
      }
      __syncthreads();   // all waves done READING X
#pragma unroll
      for (int ni = 0; ni < 4; ni++) {
        int col = wave * 64 + ni * 16 + l15;
        float bias = bAp[col];
#pragma unroll
        for (int mi = 0; mi < 4; mi++)
#pragma unroll
          for (int r = 0; r < 4; r++) {
            int rl = mi * 16 + lhi * 4 + r;
            Xs[swz(rl, col)] = f2bf_hw(fmaxf(acc[mi][ni][r] + bias, 0.f));
          }
      }
      __syncthreads();   // X now holds t
    }

    // ---- step B: h += X(t) @ w1^T + b1; X <- (relu(h) | h) ----
    {
      f32x4 acc[4][4];
#pragma unroll
      for (int mi = 0; mi < 4; mi++)
#pragma unroll
        for (int ni = 0; ni < 4; ni++) acc[mi][ni] = zero4;

      for (int kk = 0; kk < 8; ++kk) {
        const int su = ((kk * 4 + lhi) ^ (l15 & 7)) << 3;
        short8v a[4], b[4];
#pragma unroll
        for (int mi = 0; mi < 4; mi++)
          a[mi] = *(const short8v*)&Xs[(mi * 16 + l15) * 256 + su];
#pragma unroll
        for (int ni = 0; ni < 4; ni++)
          b[ni] = *(const short8v*)(wBp + (wave * 64 + ni * 16 + l15) * 256 + kk * 32 + lhi * 8);
#pragma unroll
        for (int mi = 0; mi < 4; mi++)
#pragma unroll
          for (int ni = 0; ni < 4; ni++)
            acc[mi][ni] = __builtin_amdgcn_mfma_f32_16x16x32_bf16(a[mi], b[ni], acc[mi][ni], 0, 0, 0);
      }
      __syncthreads();   // all waves done reading t
#pragma unroll
      for (int ni = 0; ni < 4; ni++) {
        int col = wave * 64 + ni * 16 + l15;
        float bias = bBp[col];
#pragma unroll
        for (int mi = 0; mi < 4; mi++)
#pragma unroll
          for (int r = 0; r < 4; r++) {
            hreg[mi][ni][r] += acc[mi][ni][r] + bias;
            float hv = hreg[mi][ni][r];
            int rl = mi * 16 + lhi * 4 + r;
            Xs[swz(rl, col)] = f2bf_hw(blk == 0 ? fmaxf(hv, 0.f) : hv);
          }
      }
      __syncthreads();
    }
  }

  // ================= Output layer + spline (no barriers) ====================
  float lad0 = 0.f, lad1 = 0.f;
  const int dsl = lane >> 5;    // dim-slot 0/1 within wave's 2 dims
  const int rsp = lane & 31;    // row within half
  unsigned short* Pw = &Pstage[wave * 1536];

  for (int chunk = 0; chunk < 4; ++chunk) {
    f32x4 acc[4][3];
#pragma unroll
    for (int mi = 0; mi < 4; mi++)
#pragma unroll
      for (int ni = 0; ni < 3; ni++) acc[mi][ni] = zero4;

    for (int kk = 0; kk < 8; ++kk) {
      const int su = ((kk * 4 + lhi) ^ (l15 & 7)) << 3;
      short8v a[4], b[3];
#pragma unroll
      for (int mi = 0; mi < 4; mi++)
        a[mi] = *(const short8v*)&Xs[(mi * 16 + l15) * 256 + su];
#pragma unroll
      for (int ni = 0; ni < 3; ni++) {
        int col = chunk * 192 + wave * 48 + ni * 16 + l15;
        b[ni] = *(const short8v*)(ws + WOUT_OFF + col * 256 + kk * 32 + lhi * 8);
      }
#pragma unroll
      for (int mi = 0; mi < 4; mi++)
#pragma unroll
        for (int ni = 0; ni < 3; ni++)
          acc[mi][ni] = __builtin_amdgcn_mfma_f32_16x16x32_bf16(a[mi], b[ni], acc[mi][ni], 0, 0, 0);
    }

#pragma unroll
    for (int hf = 0; hf < 2; ++hf) {
      // stage this wave's 2 dims x 32 rows (bf16), wave-private -> no barrier
#pragma unroll
      for (int ni = 0; ni < 3; ni++) {
        int cl = ni * 16 + l15;            // 0..47 within wave
        int ds = (cl >= 24) ? 1 : 0;
        int j  = cl - ds * 24;             // 0..23 (23 = pad)
        int dim = chunk * 8 + wave * 2 + ds;
        float bias = (j < 23) ? b_out[dim * 23 + j] : 0.f;
#pragma unroll
        for (int mi2 = 0; mi2 < 2; mi2++)
#pragma unroll
          for (int r = 0; r < 4; r++) {
            int row = mi2 * 16 + lhi * 4 + r;   // 0..31
            if (j < 23)
              Pw[ds * 768 + row * 24 + j] = f2bf_hw(acc[hf * 2 + mi2][ni][r] + bias);
          }
      }

      // spline: lane -> (row = rsp, dim = chunk*8 + wave*2 + dsl)
      {
        const float S = 0.0625f;
        int dg = chunk * 8 + wave * 2 + dsl;
        int rg = row0 + hf * 32 + rsp;
        const unsigned short* pb16 = &Pw[dsl * 768 + rsp * 24];
        short8v pv0 = *(const short8v*)(pb16);
        short8v pv1 = *(const short8v*)(pb16 + 8);
        short8v pv2 = *(const short8v*)(pb16 + 16);
        float pf[24];
#pragma unroll
        for (int i = 0; i < 8; i++) {
          pf[i]      = bf2f((unsigned short)pv0[i]);
          pf[8 + i]  = bf2f((unsigned short)pv1[i]);
          pf[16 + i] = bf2f((unsigned short)pv2[i]);
        }

        float2 xin = *(const float2*)(inp + (long)rg * 64 + 2 * dg);
        float x = xin.x, idv = xin.y;

        float pw[8], ph[8];
#pragma unroll
        for (int i = 0; i < 8; i++) { pw[i] = pf[i] * S; ph[i] = pf[8 + i] * S; }
        float mw = pw[0], mh = ph[0];
#pragma unroll
        for (int i = 1; i < 8; i++) { mw = fmaxf(mw, pw[i]); mh = fmaxf(mh, ph[i]); }
        float ew[8], eh[8], sw = 0.f, sh = 0.f;
#pragma unroll
        for (int i = 0; i < 8; i++) {
          ew[i] = __expf(pw[i] - mw); sw += ew[i];
          eh[i] = __expf(ph[i] - mh); sh += eh[i];
        }
        float invw = 0.992f * frcp(sw), invh = 0.992f * frcp(sh);

        float dv[9];
        dv[0] = 1.f; dv[8] = 1.f;
#pragma unroll
        for (int i = 1; i < 8; i++) {
          float u = pf[16 + i - 1];
          float sp = (u > 15.f) ? u : __logf(1.f + __expf(u));
          dv[i] = 0.001f + sp;
        }

        bool inside = (x >= -3.f) && (x <= 3.f);
        float xc = fminf(3.f, fmaxf(-3.f, x));

        float elo = -3.f, flo = -3.f, cw = 0.f, ch = 0.f;
        float in_cw = -3.f, in_w = 1.f, in_ch = -3.f, in_h = 1.f, in_d = 1.f, in_dp1 = 1.f;
#pragma unroll
        for (int i = 0; i < 8; i++) {
          float wi = 0.001f + ew[i] * invw; cw += wi;
          float hi = 0.001f + eh[i] * invh; ch += hi;
          float ehi = (i == 7) ? 3.f : 6.f * cw - 3.f;
          float fhi = (i == 7) ? 3.f : 6.f * ch - 3.f;
          bool take = (i == 0) || (xc >= elo);
          if (take) {
            in_cw = elo; in_w = ehi - elo;
            in_ch = flo; in_h = fhi - flo;
            in_d = dv[i]; in_dp1 = dv[i + 1];
          }
          elo = ehi; flo = fhi;
        }

        float rw   = frcp(in_w);
        float th   = (xc - in_cw) * rw;
        float omt  = 1.f - th;
        float tom  = th * omt;
        float delta = in_h * rw;
        float num  = in_h * (delta * th * th + in_d * tom);
        float den  = delta + (in_d + in_dp1 - 2.f * delta) * tom;
        float y    = in_ch + num * frcp(den);
        float dnum = delta * delta * (in_dp1 * th * th + 2.f * delta * tom + in_d * omt * omt);
        float lad  = __logf(dnum) - 2.f * __logf(den);

        float yout = inside ? y : x;
        float ladv = inside ? lad : 0.f;

        float2 o; o.x = yout; o.y = idv;
        *(float2*)(outp + (long)rg * 64 + 2 * dg) = o;

        if (hf == 0) lad0 += ladv; else lad1 += ladv;
      }
    }
  }

  // ===== lad reduction: sum dim-slots (xor 32), then across waves via LDS ===
  lad0 += __shfl_xor(lad0, 32);
  lad1 += __shfl_xor(lad1, 32);
  if (lane < 32) {
    Red[wave * 64 + lane]      = lad0;
    Red[wave * 64 + 32 + lane] = lad1;
  }
  __syncthreads();
  if (tid < 64) {
    float s = Red[tid] + Red[64 + tid] + Red[128 + tid] + Red[192 + tid];
    outp[(long)B_TOTAL * 64 + row0 + tid] = s;
  }
}

extern "C" void kernel_launch(void* const* d_in, const int* in_sizes, int n_in,
                              void* d_out, int out_size, void* d_ws, size_t ws_size,
                              hipStream_t stream) {
  const float* inputs = (const float*)d_in[0];
  const float* w_in   = (const float*)d_in[1];
  const float* b_in   = (const float*)d_in[2];
  const float* w0a    = (const float*)d_in[3];
  const float* b0a    = (const float*)d_in[4];
  const float* w1a    = (const float*)d_in[5];
  const float* b1a    = (const float*)d_in[6];
  const float* w0b    = (const float*)d_in[7];
  const float* b0b    = (const float*)d_in[8];
  const float* w1b    = (const float*)d_in[9];
  const float* b1b    = (const float*)d_in[10];
  const float* w_out  = (const float*)d_in[11];
  const float* b_out  = (const float*)d_in[12];
  unsigned short* ws  = (unsigned short*)d_ws;
  float* outp = (float*)d_out;

  prep_weights<<<dim3((WS_ELEMS + 255) / 256), dim3(256), 0, stream>>>(
      w_in, w0a, w1a, w0b, w1b, w_out, ws);
  fused_main<<<dim3(2048), dim3(256), 0, stream>>>(
      inputs, b_in, b0a, b1a, b0b, b1b, b_out, ws, outp);
}

// Round 8
// 600.035 us; speedup vs baseline: 1.0453x; 1.0453x over previous
//
#include <hip/hip_runtime.h>
#include <hip/hip_bf16.h>

// Problem constants
#define B_TOTAL 131072

typedef short short8v __attribute__((ext_vector_type(8)));
typedef float f32x4 __attribute__((ext_vector_type(4)));

__device__ __forceinline__ unsigned short f2bf(float f) {   // RNE, prep only
  union { float f; unsigned u; } v; v.f = f;
  unsigned r = v.u + 0x7FFFu + ((v.u >> 16) & 1u);
  return (unsigned short)(r >> 16);
}

__device__ __forceinline__ unsigned short f2bf_hw(float f) { // hot path: HW cast
  __hip_bfloat16 h = __float2bfloat16(f);
  return *reinterpret_cast<unsigned short*>(&h);
}

__device__ __forceinline__ float bf2f(unsigned short u) {
  union { unsigned u; float f; } v; v.u = ((unsigned)u) << 16; return v.f;
}

__device__ __forceinline__ float frcp(float x) { return __builtin_amdgcn_rcpf(x); }

// XOR-swizzled ushort index within a [64][256] bf16 tile (16B-unit swizzle).
__device__ __forceinline__ int swz(int row, int col) {
  return row * 256 + (((col >> 3) ^ (row & 7)) << 3) + (col & 7);
}

// ws layout in bf16 elements
#define W_IN_OFF   0         // 256 x 32
#define W0A_OFF    8192      // 256 x 256
#define W1A_OFF    73728
#define W0B_OFF    139264
#define W1B_OFF    204800
#define WOUT_OFF   270336    // 768 x 256 (padded: row = dim*24 + j, j==23 zero)
#define WS_ELEMS   466944

__global__ void prep_weights(const float* __restrict__ w_in,
                             const float* __restrict__ w0a,
                             const float* __restrict__ w1a,
                             const float* __restrict__ w0b,
                             const float* __restrict__ w1b,
                             const float* __restrict__ w_out,
                             unsigned short* __restrict__ ws) {
  int idx = blockIdx.x * 256 + threadIdx.x;
  if (idx >= WS_ELEMS) return;
  float v;
  if (idx < W0A_OFF)       v = w_in[idx];
  else if (idx < W1A_OFF)  v = w0a[idx - W0A_OFF];
  else if (idx < W0B_OFF)  v = w1a[idx - W1A_OFF];
  else if (idx < W1B_OFF)  v = w0b[idx - W0B_OFF];
  else if (idx < WOUT_OFF) v = w1b[idx - W1B_OFF];
  else {
    int p = idx - WOUT_OFF;
    int row = p >> 8, k = p & 255;       // row < 768
    int dim = row / 24, j = row - dim * 24;
    v = (j < 23) ? w_out[(dim * 23 + j) * 256 + k] : 0.f;
  }
  ws[idx] = f2bf(v);
}

// 64 rows/WG, 4 waves. Residual stream h held as PACKED bf16 in 32 VGPRs
// (uint2[4][4]); X (single 32KB LDS buffer) always holds plain h or t;
// ReLU applied at A-fragment READ time in step A. Wave-private bf16 spline
// staging -> no barriers in output section. LDS 45KB + regs<=170 -> 3 WG/CU.
__global__ __launch_bounds__(256, 3)
void fused_main(const float* __restrict__ inp,
                const float* __restrict__ b_in,
                const float* __restrict__ b0a, const float* __restrict__ b1a,
                const float* __restrict__ b0b, const float* __restrict__ b1b,
                const float* __restrict__ b_out,
                const unsigned short* __restrict__ ws,
                float* __restrict__ outp) {
  __shared__ unsigned short Xs[64 * 256];      // 32768 B, swizzled
  __shared__ unsigned short Pstage[4 * 1536];  // 12288 B: per-wave [ds][row][24]
  __shared__ float Red[256];                   // 1024 B lad reduction

  const int tid  = threadIdx.x;
  const int lane = tid & 63;
  const int wave = tid >> 6;       // 0..3
  const int l15  = lane & 15;
  const int lhi  = lane >> 4;      // 0..3
  const int row0 = blockIdx.x * 64;

  const f32x4 zero4 = {0.f, 0.f, 0.f, 0.f};

  uint2 hpk[4][4];   // h bf16-packed: .x = r0|r1<<16, .y = r2|r3<<16

  // ================= Layer in: h = ident @ w_in^T + b_in (K = 32) ===========
  {
    f32x4 acc[4][4];
#pragma unroll
    for (int mi = 0; mi < 4; mi++)
#pragma unroll
      for (int ni = 0; ni < 4; ni++) acc[mi][ni] = zero4;

    short8v a[4];
#pragma unroll
    for (int mi = 0; mi < 4; mi++) {
      int rg = row0 + mi * 16 + l15;
      const float2* s2 = (const float2*)(inp + (long)rg * 64) + lhi * 8;
#pragma unroll
      for (int i = 0; i < 8; i++)
        a[mi][i] = (short)f2bf_hw(s2[i].y);   // odd cols = ident
    }
    short8v b[4];
#pragma unroll
    for (int ni = 0; ni < 4; ni++) {
      int col = wave * 64 + ni * 16 + l15;
      b[ni] = *(const short8v*)(ws + W_IN_OFF + col * 32 + lhi * 8);
    }
#pragma unroll
    for (int mi = 0; mi < 4; mi++)
#pragma unroll
      for (int ni = 0; ni < 4; ni++)
        acc[mi][ni] = __builtin_amdgcn_mfma_f32_16x16x32_bf16(a[mi], b[ni], acc[mi][ni], 0, 0, 0);

    // bias; store PLAIN h bf16 -> X; pack into hpk
#pragma unroll
    for (int ni = 0; ni < 4; ni++) {
      int col = wave * 64 + ni * 16 + l15;
      float bias = b_in[col];
      unsigned short u[4];
#pragma unroll
      for (int r = 0; r < 4; r++) { /* placeholder to keep shape */ }
#pragma unroll
      for (int mi = 0; mi < 4; mi++) {
#pragma unroll
        for (int r = 0; r < 4; r++) {
          float hv = acc[mi][ni][r] + bias;
          u[r] = f2bf_hw(hv);
          int rl = mi * 16 + lhi * 4 + r;
          Xs[swz(rl, col)] = u[r];
        }
        hpk[mi][ni].x = (unsigned)u[0] | ((unsigned)u[1] << 16);
        hpk[mi][ni].y = (unsigned)u[2] | ((unsigned)u[3] << 16);
      }
    }
  }
  __syncthreads();

  // ================= 2 residual blocks (in-place X, uniform path) ===========
#pragma unroll
  for (int blk = 0; blk < 2; ++blk) {
    const unsigned short* wAp = ws + (blk == 0 ? W0A_OFF : W0B_OFF);
    const unsigned short* wBp = ws + (blk == 0 ? W1A_OFF : W1B_OFF);
    const float* bAp = (blk == 0) ? b0a : b0b;
    const float* bBp = (blk == 0) ? b1a : b1b;

    // ---- step A: t = relu( relu(X=h) @ w0^T + b0 ); X <- t ----
    {
      f32x4 acc[4][4];
#pragma unroll
      for (int mi = 0; mi < 4; mi++)
#pragma unroll
        for (int ni = 0; ni < 4; ni++) acc[mi][ni] = zero4;

      for (int kk = 0; kk < 8; ++kk) {
        const int su = ((kk * 4 + lhi) ^ (l15 & 7)) << 3;
        short8v a[4], b[4];
#pragma unroll
        for (int mi = 0; mi < 4; mi++) {
          short8v ar = *(const short8v*)&Xs[(mi * 16 + l15) * 256 + su];
#pragma unroll
          for (int i = 0; i < 8; i++) {
            unsigned short uv = (unsigned short)ar[i];
            a[mi][i] = (short)((uv & 0x8000u) ? (unsigned short)0 : uv);  // relu(bf16)
          }
        }
#pragma unroll
        for (int ni = 0; ni < 4; ni++)
          b[ni] = *(const short8v*)(wAp + (wave * 64 + ni * 16 + l15) * 256 + kk * 32 + lhi * 8);
#pragma unroll
        for (int mi = 0; mi < 4; mi++)
#pragma unroll
          for (int ni = 0; ni < 4; ni++)
            acc[mi][ni] = __builtin_amdgcn_mfma_f32_16x16x32_bf16(a[mi], b[ni], acc[mi][ni], 0, 0, 0);
      }
      __syncthreads();   // all waves done READING X
#pragma unroll
      for (int ni = 0; ni < 4; ni++) {
        int col = wave * 64 + ni * 16 + l15;
        float bias = bAp[col];
#pragma unroll
        for (int mi = 0; mi < 4; mi++)
#pragma unroll
          for (int r = 0; r < 4; r++) {
            int rl = mi * 16 + lhi * 4 + r;
            Xs[swz(rl, col)] = f2bf_hw(fmaxf(acc[mi][ni][r] + bias, 0.f));  // t (relu'd)
          }
      }
      __syncthreads();   // X now holds t
    }

    // ---- step B: h = h + X(t) @ w1^T + b1; X <- h (plain) ----
    {
      f32x4 acc[4][4];
#pragma unroll
      for (int mi = 0; mi < 4; mi++)
#pragma unroll
        for (int ni = 0; ni < 4; ni++) acc[mi][ni] = zero4;

      for (int kk = 0; kk < 8; ++kk) {
        const int su = ((kk * 4 + lhi) ^ (l15 & 7)) << 3;
        short8v a[4], b[4];
#pragma unroll
        for (int mi = 0; mi < 4; mi++)
          a[mi] = *(const short8v*)&Xs[(mi * 16 + l15) * 256 + su];   // t: no relu
#pragma unroll
        for (int ni = 0; ni < 4; ni++)
          b[ni] = *(const short8v*)(wBp + (wave * 64 + ni * 16 + l15) * 256 + kk * 32 + lhi * 8);
#pragma unroll
        for (int mi = 0; mi < 4; mi++)
#pragma unroll
          for (int ni = 0; ni < 4; ni++)
            acc[mi][ni] = __builtin_amdgcn_mfma_f32_16x16x32_bf16(a[mi], b[ni], acc[mi][ni], 0, 0, 0);
      }
      __syncthreads();   // all waves done reading t
#pragma unroll
      for (int ni = 0; ni < 4; ni++) {
        int col = wave * 64 + ni * 16 + l15;
        float bias = bBp[col];
#pragma unroll
        for (int mi = 0; mi < 4; mi++) {
          float h0 = bf2f((unsigned short)(hpk[mi][ni].x & 0xffffu));
          float h1 = bf2f((unsigned short)(hpk[mi][ni].x >> 16));
          float h2 = bf2f((unsigned short)(hpk[mi][ni].y & 0xffffu));
          float h3 = bf2f((unsigned short)(hpk[mi][ni].y >> 16));
          unsigned short u0 = f2bf_hw(h0 + acc[mi][ni][0] + bias);
          unsigned short u1 = f2bf_hw(h1 + acc[mi][ni][1] + bias);
          unsigned short u2 = f2bf_hw(h2 + acc[mi][ni][2] + bias);
          unsigned short u3 = f2bf_hw(h3 + acc[mi][ni][3] + bias);
          int rlb = mi * 16 + lhi * 4;
          Xs[swz(rlb + 0, col)] = u0;
          Xs[swz(rlb + 1, col)] = u1;
          Xs[swz(rlb + 2, col)] = u2;
          Xs[swz(rlb + 3, col)] = u3;
          hpk[mi][ni].x = (unsigned)u0 | ((unsigned)u1 << 16);
          hpk[mi][ni].y = (unsigned)u2 | ((unsigned)u3 << 16);
        }
      }
      __syncthreads();
    }
  }

  // ================= Output layer + spline (no barriers) ====================
  float lad0 = 0.f, lad1 = 0.f;
  const int dsl = lane >> 5;    // dim-slot 0/1 within wave's 2 dims
  const int rsp = lane & 31;    // row within half
  unsigned short* Pw = &Pstage[wave * 1536];

  for (int chunk = 0; chunk < 4; ++chunk) {
    f32x4 acc[4][3];
#pragma unroll
    for (int mi = 0; mi < 4; mi++)
#pragma unroll
      for (int ni = 0; ni < 3; ni++) acc[mi][ni] = zero4;

    for (int kk = 0; kk < 8; ++kk) {
      const int su = ((kk * 4 + lhi) ^ (l15 & 7)) << 3;
      short8v a[4], b[3];
#pragma unroll
      for (int mi = 0; mi < 4; mi++)
        a[mi] = *(const short8v*)&Xs[(mi * 16 + l15) * 256 + su];   // h: no relu
#pragma unroll
      for (int ni = 0; ni < 3; ni++) {
        int col = chunk * 192 + wave * 48 + ni * 16 + l15;
        b[ni] = *(const short8v*)(ws + WOUT_OFF + col * 256 + kk * 32 + lhi * 8);
      }
#pragma unroll
      for (int mi = 0; mi < 4; mi++)
#pragma unroll
        for (int ni = 0; ni < 3; ni++)
          acc[mi][ni] = __builtin_amdgcn_mfma_f32_16x16x32_bf16(a[mi], b[ni], acc[mi][ni], 0, 0, 0);
    }

#pragma unroll
    for (int hf = 0; hf < 2; ++hf) {
      // stage this wave's 2 dims x 32 rows (bf16), wave-private -> no barrier
#pragma unroll
      for (int ni = 0; ni < 3; ni++) {
        int cl = ni * 16 + l15;            // 0..47 within wave
        int ds = (cl >= 24) ? 1 : 0;
        int j  = cl - ds * 24;             // 0..23 (23 = pad)
        int dim = chunk * 8 + wave * 2 + ds;
        float bias = (j < 23) ? b_out[dim * 23 + j] : 0.f;
#pragma unroll
        for (int mi2 = 0; mi2 < 2; mi2++)
#pragma unroll
          for (int r = 0; r < 4; r++) {
            int row = mi2 * 16 + lhi * 4 + r;   // 0..31
            if (j < 23)
              Pw[ds * 768 + row * 24 + j] = f2bf_hw(acc[hf * 2 + mi2][ni][r] + bias);
          }
      }

      // spline: lane -> (row = rsp, dim = chunk*8 + wave*2 + dsl)
      {
        const float S = 0.0625f;
        int dg = chunk * 8 + wave * 2 + dsl;
        int rg = row0 + hf * 32 + rsp;
        const unsigned short* pb16 = &Pw[dsl * 768 + rsp * 24];
        short8v pv0 = *(const short8v*)(pb16);
        short8v pv1 = *(const short8v*)(pb16 + 8);
        short8v pv2 = *(const short8v*)(pb16 + 16);
        float pf[24];
#pragma unroll
        for (int i = 0; i < 8; i++) {
          pf[i]      = bf2f((unsigned short)pv0[i]);
          pf[8 + i]  = bf2f((unsigned short)pv1[i]);
          pf[16 + i] = bf2f((unsigned short)pv2[i]);
        }

        float2 xin = *(const float2*)(inp + (long)rg * 64 + 2 * dg);
        float x = xin.x, idv = xin.y;

        float pw[8], ph[8];
#pragma unroll
        for (int i = 0; i < 8; i++) { pw[i] = pf[i] * S; ph[i] = pf[8 + i] * S; }
        float mw = pw[0], mh = ph[0];
#pragma unroll
        for (int i = 1; i < 8; i++) { mw = fmaxf(mw, pw[i]); mh = fmaxf(mh, ph[i]); }
        float ew[8], eh[8], sw = 0.f, sh = 0.f;
#pragma unroll
        for (int i = 0; i < 8; i++) {
          ew[i] = __expf(pw[i] - mw); sw += ew[i];
          eh[i] = __expf(ph[i] - mh); sh += eh[i];
        }
        float invw = 0.992f * frcp(sw), invh = 0.992f * frcp(sh);

        float dv[9];
        dv[0] = 1.f; dv[8] = 1.f;
#pragma unroll
        for (int i = 1; i < 8; i++) {
          float u = pf[16 + i - 1];
          float sp = (u > 15.f) ? u : __logf(1.f + __expf(u));
          dv[i] = 0.001f + sp;
        }

        bool inside = (x >= -3.f) && (x <= 3.f);
        float xc = fminf(3.f, fmaxf(-3.f, x));

        float elo = -3.f, flo = -3.f, cw = 0.f, ch = 0.f;
        float in_cw = -3.f, in_w = 1.f, in_ch = -3.f, in_h = 1.f, in_d = 1.f, in_dp1 = 1.f;
#pragma unroll
        for (int i = 0; i < 8; i++) {
          float wi = 0.001f + ew[i] * invw; cw += wi;
          float hi = 0.001f + eh[i] * invh; ch += hi;
          float ehi = (i == 7) ? 3.f : 6.f * cw - 3.f;
          float fhi = (i == 7) ? 3.f : 6.f * ch - 3.f;
          bool take = (i == 0) || (xc >= elo);
          if (take) {
            in_cw = elo; in_w = ehi - elo;
            in_ch = flo; in_h = fhi - flo;
            in_d = dv[i]; in_dp1 = dv[i + 1];
          }
          elo = ehi; flo = fhi;
        }

        float rw   = frcp(in_w);
        float th   = (xc - in_cw) * rw;
        float omt  = 1.f - th;
        float tom  = th * omt;
        float delta = in_h * rw;
        float num  = in_h * (delta * th * th + in_d * tom);
        float den  = delta + (in_d + in_dp1 - 2.f * delta) * tom;
        float y    = in_ch + num * frcp(den);
        float dnum = delta * delta * (in_dp1 * th * th + 2.f * delta * tom + in_d * omt * omt);
        float lad  = __logf(dnum) - 2.f * __logf(den);

        float yout = inside ? y : x;
        float ladv = inside ? lad : 0.f;

        float2 o; o.x = yout; o.y = idv;
        *(float2*)(outp + (long)rg * 64 + 2 * dg) = o;

        if (hf == 0) lad0 += ladv; else lad1 += ladv;
      }
    }
  }

  // ===== lad reduction: sum dim-slots (xor 32), then across waves via LDS ===
  lad0 += __shfl_xor(lad0, 32);
  lad1 += __shfl_xor(lad1, 32);
  if (lane < 32) {
    Red[wave * 64 + lane]      = lad0;
    Red[wave * 64 + 32 + lane] = lad1;
  }
  __syncthreads();
  if (tid < 64) {
    float s = Red[tid] + Red[64 + tid] + Red[128 + tid] + Red[192 + tid];
    outp[(long)B_TOTAL * 64 + row0 + tid] = s;
  }
}

extern "C" void kernel_launch(void* const* d_in, const int* in_sizes, int n_in,
                              void* d_out, int out_size, void* d_ws, size_t ws_size,
                              hipStream_t stream) {
  const float* inputs = (const float*)d_in[0];
  const float* w_in   = (const float*)d_in[1];
  const float* b_in   = (const float*)d_in[2];
  const float* w0a    = (const float*)d_in[3];
  const float* b0a    = (const float*)d_in[4];
  const float* w1a    = (const float*)d_in[5];
  const float* b1a    = (const float*)d_in[6];
  const float* w0b    = (const float*)d_in[7];
  const float* b0b    = (const float*)d_in[8];
  const float* w1b    = (const float*)d_in[9];
  const float* b1b    = (const float*)d_in[10];
  const float* w_out  = (const float*)d_in[11];
  const float* b_out  = (const float*)d_in[12];
  unsigned short* ws  = (unsigned short*)d_ws;
  float* outp = (float*)d_out;

  prep_weights<<<dim3((WS_ELEMS + 255) / 256), dim3(256), 0, stream>>>(
      w_in, w0a, w1a, w0b, w1b, w_out, ws);
  fused_main<<<dim3(2048), dim3(256), 0, stream>>>(
      inputs, b_in, b0a, b1a, b0b, b1b, b_out, ws, outp);
}

// Round 9
// 382.578 us; speedup vs baseline: 1.6395x; 1.5684x over previous
//
#include <hip/hip_runtime.h>
#include <hip/hip_bf16.h>

// Problem constants
#define B_TOTAL 131072

typedef short short8v __attribute__((ext_vector_type(8)));
typedef float f32x4 __attribute__((ext_vector_type(4)));

__device__ __forceinline__ unsigned short f2bf(float f) {   // RNE, prep only
  union { float f; unsigned u; } v; v.f = f;
  unsigned r = v.u + 0x7FFFu + ((v.u >> 16) & 1u);
  return (unsigned short)(r >> 16);
}

__device__ __forceinline__ unsigned short f2bf_hw(float f) { // hot path: HW cast
  __hip_bfloat16 h = __float2bfloat16(f);
  return *reinterpret_cast<unsigned short*>(&h);
}

__device__ __forceinline__ float bf2f(unsigned short u) {
  union { unsigned u; float f; } v; v.u = ((unsigned)u) << 16; return v.f;
}

__device__ __forceinline__ float frcp(float x) { return __builtin_amdgcn_rcpf(x); }

// XOR-swizzled ushort index within a [64][256] bf16 tile (16B-unit swizzle).
__device__ __forceinline__ int swz(int row, int col) {
  return row * 256 + (((col >> 3) ^ (row & 7)) << 3) + (col & 7);
}

// ws layout in bf16 elements
#define W_IN_OFF   0         // 256 x 32
#define W0A_OFF    8192      // 256 x 256
#define W1A_OFF    73728
#define W0B_OFF    139264
#define W1B_OFF    204800
#define WOUT_OFF   270336    // 768 x 256 (padded: row = dim*24 + j, j==23 zero)
#define WS_ELEMS   466944

__global__ void prep_weights(const float* __restrict__ w_in,
                             const float* __restrict__ w0a,
                             const float* __restrict__ w1a,
                             const float* __restrict__ w0b,
                             const float* __restrict__ w1b,
                             const float* __restrict__ w_out,
                             unsigned short* __restrict__ ws) {
  int idx = blockIdx.x * 256 + threadIdx.x;
  if (idx >= WS_ELEMS) return;
  float v;
  if (idx < W0A_OFF)       v = w_in[idx];
  else if (idx < W1A_OFF)  v = w0a[idx - W0A_OFF];
  else if (idx < W0B_OFF)  v = w1a[idx - W1A_OFF];
  else if (idx < W1B_OFF)  v = w0b[idx - W0B_OFF];
  else if (idx < WOUT_OFF) v = w1b[idx - W1B_OFF];
  else {
    int p = idx - WOUT_OFF;
    int row = p >> 8, k = p & 255;       // row < 768
    int dim = row / 24, j = row - dim * 24;
    v = (j < 23) ? w_out[(dim * 23 + j) * 256 + k] : 0.f;
  }
  ws[idx] = f2bf(v);
}

// 64 rows/WG, 4 waves. fp32 h in registers (r5/r6 plan, launch_bounds(256,2):
// allocator picks ~128 arch VGPRs, no spills). Single in-place 32KB X buffer
// (read-done barrier -> overwrite). Wave-private bf16 spline staging (no
// barriers in output section). LDS 46080 B -> 3 blocks/CU (LDS-limited).
__global__ __launch_bounds__(256, 2)
void fused_main(const float* __restrict__ inp,
                const float* __restrict__ b_in,
                const float* __restrict__ b0a, const float* __restrict__ b1a,
                const float* __restrict__ b0b, const float* __restrict__ b1b,
                const float* __restrict__ b_out,
                const unsigned short* __restrict__ ws,
                float* __restrict__ outp) {
  __shared__ unsigned short Xs[64 * 256];      // 32768 B, swizzled
  __shared__ unsigned short Pstage[4 * 1536];  // 12288 B: per-wave [ds][row][24]
  __shared__ float Red[256];                   // 1024 B lad reduction

  const int tid  = threadIdx.x;
  const int lane = tid & 63;
  const int wave = tid >> 6;       // 0..3
  const int l15  = lane & 15;
  const int lhi  = lane >> 4;      // 0..3
  const int row0 = blockIdx.x * 64;

  const f32x4 zero4 = {0.f, 0.f, 0.f, 0.f};

  f32x4 hreg[4][4];   // fp32 h: row mi*16+lhi*4+r, col wave*64+ni*16+l15

  // ================= Layer in: h = ident @ w_in^T + b_in (K = 32) ===========
  {
#pragma unroll
    for (int mi = 0; mi < 4; mi++)
#pragma unroll
      for (int ni = 0; ni < 4; ni++) hreg[mi][ni] = zero4;

    short8v a[4];
#pragma unroll
    for (int mi = 0; mi < 4; mi++) {
      int rg = row0 + mi * 16 + l15;
      const float2* s2 = (const float2*)(inp + (long)rg * 64) + lhi * 8;
#pragma unroll
      for (int i = 0; i < 8; i++)
        a[mi][i] = (short)f2bf_hw(s2[i].y);   // odd cols = ident
    }
    short8v b[4];
#pragma unroll
    for (int ni = 0; ni < 4; ni++) {
      int col = wave * 64 + ni * 16 + l15;
      b[ni] = *(const short8v*)(ws + W_IN_OFF + col * 32 + lhi * 8);
    }
#pragma unroll
    for (int mi = 0; mi < 4; mi++)
#pragma unroll
      for (int ni = 0; ni < 4; ni++)
        hreg[mi][ni] = __builtin_amdgcn_mfma_f32_16x16x32_bf16(a[mi], b[ni], hreg[mi][ni], 0, 0, 0);

    // bias; write relu(h) bf16 -> X (stepA input)
#pragma unroll
    for (int ni = 0; ni < 4; ni++) {
      int col = wave * 64 + ni * 16 + l15;
      float bias = b_in[col];
#pragma unroll
      for (int mi = 0; mi < 4; mi++)
#pragma unroll
        for (int r = 0; r < 4; r++) {
          hreg[mi][ni][r] += bias;
          int rl = mi * 16 + lhi * 4 + r;
          Xs[swz(rl, col)] = f2bf_hw(fmaxf(hreg[mi][ni][r], 0.f));
        }
    }
  }
  __syncthreads();

  // ================= 2 residual blocks (in-place X) =========================
#pragma unroll
  for (int blk = 0; blk < 2; ++blk) {
    const unsigned short* wAp = ws + (blk == 0 ? W0A_OFF : W0B_OFF);
    const unsigned short* wBp = ws + (blk == 0 ? W1A_OFF : W1B_OFF);
    const float* bAp = (blk == 0) ? b0a : b0b;
    const float* bBp = (blk == 0) ? b1a : b1b;

    // ---- step A: t = relu( X(relu h) @ w0^T + b0 ); X <- t ----
    {
      f32x4 acc[4][4];
#pragma unroll
      for (int mi = 0; mi < 4; mi++)
#pragma unroll
        for (int ni = 0; ni < 4; ni++) acc[mi][ni] = zero4;

      for (int kk = 0; kk < 8; ++kk) {
        const int su = ((kk * 4 + lhi) ^ (l15 & 7)) << 3;
        short8v a[4], b[4];
#pragma unroll
        for (int mi = 0; mi < 4; mi++)
          a[mi] = *(const short8v*)&Xs[(mi * 16 + l15) * 256 + su];
#pragma unroll
        for (int ni = 0; ni < 4; ni++)
          b[ni] = *(const short8v*)(wAp + (wave * 64 + ni * 16 + l15) * 256 + kk * 32 + lhi * 8);
#pragma unroll
        for (int mi = 0; mi < 4; mi++)
#pragma unroll
          for (int ni = 0; ni < 4; ni++)
            acc[mi][ni] = __builtin_amdgcn_mfma_f32_16x16x32_bf16(a[mi], b[ni], acc[mi][ni], 0, 0, 0);
      }
      __syncthreads();   // all waves done READING X
#pragma unroll
      for (int ni = 0; ni < 4; ni++) {
        int col = wave * 64 + ni * 16 + l15;
        float bias = bAp[col];
#pragma unroll
        for (int mi = 0; mi < 4; mi++)
#pragma unroll
          for (int r = 0; r < 4; r++) {
            int rl = mi * 16 + lhi * 4 + r;
            Xs[swz(rl, col)] = f2bf_hw(fmaxf(acc[mi][ni][r] + bias, 0.f));  // t
          }
      }
      __syncthreads();   // X now holds t
    }

    // ---- step B: h += X(t) @ w1^T + b1; X <- (relu(h) | h) ----
    {
      f32x4 acc[4][4];
#pragma unroll
      for (int mi = 0; mi < 4; mi++)
#pragma unroll
        for (int ni = 0; ni < 4; ni++) acc[mi][ni] = zero4;

      for (int kk = 0; kk < 8; ++kk) {
        const int su = ((kk * 4 + lhi) ^ (l15 & 7)) << 3;
        short8v a[4], b[4];
#pragma unroll
        for (int mi = 0; mi < 4; mi++)
          a[mi] = *(const short8v*)&Xs[(mi * 16 + l15) * 256 + su];
#pragma unroll
        for (int ni = 0; ni < 4; ni++)
          b[ni] = *(const short8v*)(wBp + (wave * 64 + ni * 16 + l15) * 256 + kk * 32 + lhi * 8);
#pragma unroll
        for (int mi = 0; mi < 4; mi++)
#pragma unroll
          for (int ni = 0; ni < 4; ni++)
            acc[mi][ni] = __builtin_amdgcn_mfma_f32_16x16x32_bf16(a[mi], b[ni], acc[mi][ni], 0, 0, 0);
      }
      __syncthreads();   // all waves done reading t
#pragma unroll
      for (int ni = 0; ni < 4; ni++) {
        int col = wave * 64 + ni * 16 + l15;
        float bias = bBp[col];
#pragma unroll
        for (int mi = 0; mi < 4; mi++)
#pragma unroll
          for (int r = 0; r < 4; r++) {
            hreg[mi][ni][r] += acc[mi][ni][r] + bias;
            float hv = hreg[mi][ni][r];
            int rl = mi * 16 + lhi * 4 + r;
            Xs[swz(rl, col)] = f2bf_hw(blk == 0 ? fmaxf(hv, 0.f) : hv);
          }
      }
      __syncthreads();
    }
  }

  // ================= Output layer + spline (no barriers) ====================
  float lad0 = 0.f, lad1 = 0.f;
  const int dsl = lane >> 5;    // dim-slot 0/1 within wave's 2 dims
  const int rsp = lane & 31;    // row within half
  unsigned short* Pw = &Pstage[wave * 1536];

  for (int chunk = 0; chunk < 4; ++chunk) {
    f32x4 acc[4][3];
#pragma unroll
    for (int mi = 0; mi < 4; mi++)
#pragma unroll
      for (int ni = 0; ni < 3; ni++) acc[mi][ni] = zero4;

    for (int kk = 0; kk < 8; ++kk) {
      const int su = ((kk * 4 + lhi) ^ (l15 & 7)) << 3;
      short8v a[4], b[3];
#pragma unroll
      for (int mi = 0; mi < 4; mi++)
        a[mi] = *(const short8v*)&Xs[(mi * 16 + l15) * 256 + su];   // h: no relu
#pragma unroll
      for (int ni = 0; ni < 3; ni++) {
        int col = chunk * 192 + wave * 48 + ni * 16 + l15;
        b[ni] = *(const short8v*)(ws + WOUT_OFF + col * 256 + kk * 32 + lhi * 8);
      }
#pragma unroll
      for (int mi = 0; mi < 4; mi++)
#pragma unroll
        for (int ni = 0; ni < 3; ni++)
          acc[mi][ni] = __builtin_amdgcn_mfma_f32_16x16x32_bf16(a[mi], b[ni], acc[mi][ni], 0, 0, 0);
    }

#pragma unroll
    for (int hf = 0; hf < 2; ++hf) {
      // stage this wave's 2 dims x 32 rows (bf16), wave-private -> no barrier
#pragma unroll
      for (int ni = 0; ni < 3; ni++) {
        int cl = ni * 16 + l15;            // 0..47 within wave
        int ds = (cl >= 24) ? 1 : 0;
        int j  = cl - ds * 24;             // 0..23 (23 = pad)
        int dim = chunk * 8 + wave * 2 + ds;
        float bias = (j < 23) ? b_out[dim * 23 + j] : 0.f;
#pragma unroll
        for (int mi2 = 0; mi2 < 2; mi2++)
#pragma unroll
          for (int r = 0; r < 4; r++) {
            int row = mi2 * 16 + lhi * 4 + r;   // 0..31
            if (j < 23)
              Pw[ds * 768 + row * 24 + j] = f2bf_hw(acc[hf * 2 + mi2][ni][r] + bias);
          }
      }

      // spline: lane -> (row = rsp, dim = chunk*8 + wave*2 + dsl)
      {
        const float S = 0.0625f;
        int dg = chunk * 8 + wave * 2 + dsl;
        int rg = row0 + hf * 32 + rsp;
        const unsigned short* pb16 = &Pw[dsl * 768 + rsp * 24];
        short8v pv0 = *(const short8v*)(pb16);
        short8v pv1 = *(const short8v*)(pb16 + 8);
        short8v pv2 = *(const short8v*)(pb16 + 16);
        float pf[24];
#pragma unroll
        for (int i = 0; i < 8; i++) {
          pf[i]      = bf2f((unsigned short)pv0[i]);
          pf[8 + i]  = bf2f((unsigned short)pv1[i]);
          pf[16 + i] = bf2f((unsigned short)pv2[i]);
        }

        float2 xin = *(const float2*)(inp + (long)rg * 64 + 2 * dg);
        float x = xin.x, idv = xin.y;

        float pw[8], ph[8];
#pragma unroll
        for (int i = 0; i < 8; i++) { pw[i] = pf[i] * S; ph[i] = pf[8 + i] * S; }
        float mw = pw[0], mh = ph[0];
#pragma unroll
        for (int i = 1; i < 8; i++) { mw = fmaxf(mw, pw[i]); mh = fmaxf(mh, ph[i]); }
        float ew[8], eh[8], sw = 0.f, sh = 0.f;
#pragma unroll
        for (int i = 0; i < 8; i++) {
          ew[i] = __expf(pw[i] - mw); sw += ew[i];
          eh[i] = __expf(ph[i] - mh); sh += eh[i];
        }
        float invw = 0.992f * frcp(sw), invh = 0.992f * frcp(sh);

        float dv[9];
        dv[0] = 1.f; dv[8] = 1.f;
#pragma unroll
        for (int i = 1; i < 8; i++) {
          float u = pf[16 + i - 1];
          float sp = (u > 15.f) ? u : __logf(1.f + __expf(u));
          dv[i] = 0.001f + sp;
        }

        bool inside = (x >= -3.f) && (x <= 3.f);
        float xc = fminf(3.f, fmaxf(-3.f, x));

        float elo = -3.f, flo = -3.f, cw = 0.f, ch = 0.f;
        float in_cw = -3.f, in_w = 1.f, in_ch = -3.f, in_h = 1.f, in_d = 1.f, in_dp1 = 1.f;
#pragma unroll
        for (int i = 0; i < 8; i++) {
          float wi = 0.001f + ew[i] * invw; cw += wi;
          float hi = 0.001f + eh[i] * invh; ch += hi;
          float ehi = (i == 7) ? 3.f : 6.f * cw - 3.f;
          float fhi = (i == 7) ? 3.f : 6.f * ch - 3.f;
          bool take = (i == 0) || (xc >= elo);
          if (take) {
            in_cw = elo; in_w = ehi - elo;
            in_ch = flo; in_h = fhi - flo;
            in_d = dv[i]; in_dp1 = dv[i + 1];
          }
          elo = ehi; flo = fhi;
        }

        float rw   = frcp(in_w);
        float th   = (xc - in_cw) * rw;
        float omt  = 1.f - th;
        float tom  = th * omt;
        float delta = in_h * rw;
        float num  = in_h * (delta * th * th + in_d * tom);
        float den  = delta + (in_d + in_dp1 - 2.f * delta) * tom;
        float y    = in_ch + num * frcp(den);
        float dnum = delta * delta * (in_dp1 * th * th + 2.f * delta * tom + in_d * omt * omt);
        float lad  = __logf(dnum) - 2.f * __logf(den);

        float yout = inside ? y : x;
        float ladv = inside ? lad : 0.f;

        float2 o; o.x = yout; o.y = idv;
        *(float2*)(outp + (long)rg * 64 + 2 * dg) = o;

        if (hf == 0) lad0 += ladv; else lad1 += ladv;
      }
    }
  }

  // ===== lad reduction: sum dim-slots (xor 32), then across waves via LDS ===
  lad0 += __shfl_xor(lad0, 32);
  lad1 += __shfl_xor(lad1, 32);
  if (lane < 32) {
    Red[wave * 64 + lane]      = lad0;
    Red[wave * 64 + 32 + lane] = lad1;
  }
  __syncthreads();
  if (tid < 64) {
    float s = Red[tid] + Red[64 + tid] + Red[128 + tid] + Red[192 + tid];
    outp[(long)B_TOTAL * 64 + row0 + tid] = s;
  }
}

extern "C" void kernel_launch(void* const* d_in, const int* in_sizes, int n_in,
                              void* d_out, int out_size, void* d_ws, size_t ws_size,
                              hipStream_t stream) {
  const float* inputs = (const float*)d_in[0];
  const float* w_in   = (const float*)d_in[1];
  const float* b_in   = (const float*)d_in[2];
  const float* w0a    = (const float*)d_in[3];
  const float* b0a    = (const float*)d_in[4];
  const float* w1a    = (const float*)d_in[5];
  const float* b1a    = (const float*)d_in[6];
  const float* w0b    = (const float*)d_in[7];
  const float* b0b    = (const float*)d_in[8];
  const float* w1b    = (const float*)d_in[9];
  const float* b1b    = (const float*)d_in[10];
  const float* w_out  = (const float*)d_in[11];
  const float* b_out  = (const float*)d_in[12];
  unsigned short* ws  = (unsigned short*)d_ws;
  float* outp = (float*)d_out;

  prep_weights<<<dim3((WS_ELEMS + 255) / 256), dim3(256), 0, stream>>>(
      w_in, w0a, w1a, w0b, w1b, w_out, ws);
  fused_main<<<dim3(2048), dim3(256), 0, stream>>>(
      inputs, b_in, b0a, b1a, b0b, b1b, b_out, ws, outp);
}